// Round 2
// baseline (95.699 us; speedup 1.0000x reference)
//
#include <hip/hip_runtime.h>

// Problem constants (reference: NUM_EMBEDDINGS=8192, EMBEDDING_DIM=512, BATCH=16384)
#define NUM_EMB    8192
#define EMB_DIM    512
#define BATCH_N    16384
#define BD         (BATCH_N * EMB_DIM)   // 8388608 elements in quantized (and diff)
#define TOTAL_OUT  (2 * BD + 1)          // 16777217 fp32 elements in d_out
#define NCHUNK     (TOTAL_OUT / 4)       // 4194304 full float4 chunks (+1 tail float)
#define QCHUNK_END (BD / 4)              // 2097152: chunk holding the last quantized elem
#define NBLK_SUM   2048

// Cross-kernel scratch that does NOT rely on d_ws (d_ws proved unusable in R1):
// every block of vq_sum unconditionally writes its slot, so no zeroing needed.
__device__ float g_partial[NBLK_SUM];

// Kernel A: per-block partial sums of W^2 (fp32 W, 8192x512 = 16 MB).
__global__ void vq_sum(const float* __restrict__ W) {
    int tid = blockIdx.x * blockDim.x + threadIdx.x;   // 524288 threads
    const float4* W4 = (const float4*)W;               // 1048576 float4s -> 2/thread
    float s = 0.0f;
#pragma unroll
    for (int r = 0; r < 2; ++r) {
        float4 v = W4[tid + r * (NBLK_SUM * 256)];
        s = fmaf(v.x, v.x, s);
        s = fmaf(v.y, v.y, s);
        s = fmaf(v.z, v.z, s);
        s = fmaf(v.w, v.w, s);
    }
    // wave64 reduce
#pragma unroll
    for (int off = 32; off > 0; off >>= 1) s += __shfl_down(s, off, 64);
    __shared__ float ls[4];
    int lane = threadIdx.x & 63, wv = threadIdx.x >> 6;
    if (lane == 0) ls[wv] = s;
    __syncthreads();
    if (threadIdx.x == 0) g_partial[blockIdx.x] = ls[0] + ls[1] + ls[2] + ls[3];
}

// Kernel B: write d_out = [loss | quantized = W[x] | diff = 0] as aligned float4
// chunks. Chunk c covers out elements e = 4c..4c+3; quantized index i = e - 1.
__global__ void vq_write(const int* __restrict__ x, const float* __restrict__ W,
                         float* __restrict__ out) {
    int c = blockIdx.x * blockDim.x + threadIdx.x;

    float loss = 0.0f;
    if (blockIdx.x == 0) {
        // block 0 reduces the 2048 partials (only thread c==0 will use the result)
        __shared__ float red[256];
        float s = 0.0f;
        for (int i = threadIdx.x; i < NBLK_SUM; i += 256) s += g_partial[i];
        red[threadIdx.x] = s;
        __syncthreads();
        for (int st = 128; st > 0; st >>= 1) {
            if (threadIdx.x < st) red[threadIdx.x] += red[threadIdx.x + st];
            __syncthreads();
        }
        loss = 0.25f * red[0];   // COMMITMENT_COST * sum(W^2); diff-term is exactly 0
    }

    float4* out4 = (float4*)out;
    if (c >= 1 && c < QCHUNK_END) {
        // interior quantized chunk: i = 4c-1 .. 4c+2
        int i0 = 4 * c - 1;
        int b0 = i0 >> 9, j0 = i0 & 511;       // misphased first element
        int b1 = c >> 7,  j1 = (4 * c) & 511;  // j1 % 4 == 0 and j1 <= 508
        int k0 = x[b0];
        int k1 = x[b1];
        float w0 = W[k0 * EMB_DIM + j0];
        float4 v = *(const float4*)(W + k1 * EMB_DIM + j1);  // 16B-aligned, in-row
        out4[c] = make_float4(w0, v.x, v.y, v.z);
    } else if (c > QCHUNK_END && c < NCHUNK) {
        // diff region: exact zeros
        out4[c] = make_float4(0.0f, 0.0f, 0.0f, 0.0f);
    } else if (c == 0) {
        // [loss, quantized[0..2]] = [loss, W[x[0]][0..2]]
        int k = x[0];
        float4 v = *(const float4*)(W + k * EMB_DIM);
        out4[0] = make_float4(loss, v.x, v.y, v.z);
    } else if (c == QCHUNK_END) {
        // e=8388608 is quantized last element (b=BATCH-1, j=511); rest are diff=0
        float w = W[x[BATCH_N - 1] * EMB_DIM + 511];
        out4[c] = make_float4(w, 0.0f, 0.0f, 0.0f);
    } else if (c == NCHUNK) {
        // final odd element (last diff element)
        out[TOTAL_OUT - 1] = 0.0f;
    }
}

extern "C" void kernel_launch(void* const* d_in, const int* in_sizes, int n_in,
                              void* d_out, int out_size, void* d_ws, size_t ws_size,
                              hipStream_t stream) {
    const int*   x = (const int*)d_in[0];    // int32 indices, 16384
    const float* W = (const float*)d_in[1];  // fp32 codebook, 8192*512
    float* out     = (float*)d_out;          // fp32: [loss | quantized | diff]

    vq_sum<<<NBLK_SUM, 256, 0, stream>>>(W);

    int blocks = (NCHUNK + 1 + 255) / 256;   // 16385
    vq_write<<<blocks, 256, 0, stream>>>(x, W, out);
}